// Round 6
// baseline (592.708 us; speedup 1.0000x reference)
//
#include <hip/hip_runtime.h>
#include <hip/hip_bf16.h>

#define N_  100000
#define F_  5
#define D_  128
#define H_  4
#define HD_ 32
#define E_  800000
#define NT_ 32

typedef __attribute__((ext_vector_type(8))) short bf16x8;
typedef __attribute__((ext_vector_type(4))) float f32x4;

__device__ __forceinline__ unsigned short f2bf(float f) {
  unsigned u = __float_as_uint(f);
  u += 0x7FFF + ((u >> 16) & 1);          // round-to-nearest-even
  return (unsigned short)(u >> 16);
}

__device__ __forceinline__ unsigned pk2(float a, float b) {
  __hip_bfloat162 h = __float22bfloat162_rn(make_float2(a, b));  // v_cvt_pk_bf16_f32
  return *(unsigned*)&h;
}

// ---------------------------------------------------------------------------
// Fragment-direct bf16 MFMA GEMM: Y = act(X @ W + bias) (+Res), fp32 I/O.
// A-operand = W^T (LDS, staged once per block), B-operand = X (DIRECT from
// global, per-lane k-contiguous 16B chunks that tile into 64B segments).
// No barriers in the K-loop -> compiler pipelines loads across MFMAs.
// C/D: col(lane&15)=node, row=(lane>>4)*4+reg=feature -> float4 epilogue.
// ---------------------------------------------------------------------------
template<int K, int M, bool RELU, bool RES>
__global__ __launch_bounds__(256) void mfma_gemm(
    const float* __restrict__ X, const float* __restrict__ W,
    const float* __restrict__ bias, const float* __restrict__ Res,
    float* __restrict__ Y)
{
  constexpr int SB = K + 8;     // W^T row stride (bf16): 16B-aligned rows, 2-way banks
  constexpr int FH = M / 2;     // features per wave
  constexpr int IF = M / 32;    // 16-feature tiles per wave (4 or 2)

  __shared__ unsigned short sWT[M * SB];

  const int t = threadIdx.x;
  const int node0 = blockIdx.x * 128;
  const int lane = t & 63;
  const int w  = t >> 6;
  const int wr = w >> 1, wc = w & 1;        // feature-half, node-half
  const int l16 = lane & 15, kg = lane >> 4;

  // ---- one-time: W[k][m] -> sWT[m][k] (bf16) ----
  #pragma unroll
  for (int i = 0; i < (K * M / 4) / 256; ++i) {
    const int idx = t + 256 * i;
    const int k  = idx / (M / 4);
    const int m0 = (idx % (M / 4)) * 4;
    const float4 wv = ((const float4*)W)[idx];
    sWT[(m0 + 0) * SB + k] = f2bf(wv.x);
    sWT[(m0 + 1) * SB + k] = f2bf(wv.y);
    sWT[(m0 + 2) * SB + k] = f2bf(wv.z);
    sWT[(m0 + 3) * SB + k] = f2bf(wv.w);
  }

  f32x4 acc[IF][4];
  #pragma unroll
  for (int i = 0; i < IF; ++i)
    #pragma unroll
    for (int j = 0; j < 4; ++j) acc[i][j] = (f32x4){0.f, 0.f, 0.f, 0.f};

  // node index this lane covers in tile j: node0 + wc*64 + j*16 + l16
  const int nbase = node0 + wc * 64 + l16;

  __syncthreads();

  #pragma unroll
  for (int k0 = 0; k0 < K; k0 += 32) {
    const int kk = k0 + kg * 8;
    bf16x8 aw[IF];
    #pragma unroll
    for (int i = 0; i < IF; ++i)
      aw[i] = *(const bf16x8*)&sWT[(wr * FH + i * 16 + l16) * SB + kk];
    #pragma unroll
    for (int j = 0; j < 4; ++j) {
      const int node = nbase + j * 16;
      float4 x0, x1;
      if (node < N_) {
        x0 = *(const float4*)&X[(long)node * K + kk];
        x1 = *(const float4*)&X[(long)node * K + kk + 4];
      } else {
        x0 = make_float4(0.f, 0.f, 0.f, 0.f);
        x1 = x0;
      }
      union { uint4 u; bf16x8 v; } bx;
      bx.u.x = pk2(x0.x, x0.y);
      bx.u.y = pk2(x0.z, x0.w);
      bx.u.z = pk2(x1.x, x1.y);
      bx.u.w = pk2(x1.z, x1.w);
      #pragma unroll
      for (int i = 0; i < IF; ++i)
        acc[i][j] = __builtin_amdgcn_mfma_f32_16x16x32_bf16(aw[i], bx.v, acc[i][j], 0, 0, 0);
    }
  }

  // ---- epilogue: lane writes 4 consecutive features of its node ----
  float4 b4[IF];
  #pragma unroll
  for (int i = 0; i < IF; ++i)
    b4[i] = *(const float4*)&bias[wr * FH + i * 16 + kg * 4];

  #pragma unroll
  for (int j = 0; j < 4; ++j) {
    const int node = nbase + j * 16;
    if (node >= N_) continue;
    #pragma unroll
    for (int i = 0; i < IF; ++i) {
      const int f0 = wr * FH + i * 16 + kg * 4;
      float4 o = make_float4(acc[i][j][0] + b4[i].x, acc[i][j][1] + b4[i].y,
                             acc[i][j][2] + b4[i].z, acc[i][j][3] + b4[i].w);
      if constexpr (RELU) {
        o.x = fmaxf(o.x, 0.f); o.y = fmaxf(o.y, 0.f);
        o.z = fmaxf(o.z, 0.f); o.w = fmaxf(o.w, 0.f);
      }
      if constexpr (RES) {
        const float4 r = *(const float4*)&Res[(long)node * M + f0];
        o.x += r.x; o.y += r.y; o.z += r.z; o.w += r.w;
      }
      *(float4*)&Y[(long)node * M + f0] = o;
    }
  }
}

// ---------------------------------------------------------------------------
// Small-K GEMM (K=5), fp32.
// ---------------------------------------------------------------------------
template<int K, int M, bool RELU>
__global__ __launch_bounds__(128) void gemm_small(
    const float* __restrict__ X, const float* __restrict__ W,
    const float* __restrict__ bias, float* __restrict__ Y)
{
  constexpr int FG  = M / 4;
  constexpr int NG  = 128 / FG;
  constexpr int NPT = NT_ / NG;

  __shared__ float sxT[K * 33];
  __shared__ float sw[K * M];
  __shared__ float sb[M];

  const int t = threadIdx.x;
  const long node0 = (long)blockIdx.x * NT_;

  for (int i = t; i < NT_ * K; i += 128) {
    int n = i / K, k = i % K;
    sxT[k * 33 + n] = X[(node0 + n) * K + k];
  }
  for (int i = t; i < K * M; i += 128) sw[i] = W[i];
  if (t < M) sb[t] = bias[t];
  __syncthreads();

  const int tf = t % FG;
  const int tn = t / FG;
  float acc[NPT][4];
  #pragma unroll
  for (int n = 0; n < NPT; ++n)
    #pragma unroll
    for (int f = 0; f < 4; ++f) acc[n][f] = sb[tf * 4 + f];

  #pragma unroll
  for (int j = 0; j < K; ++j) {
    const float4 wv = *(const float4*)&sw[j * M + tf * 4];
    #pragma unroll
    for (int n = 0; n < NPT; ++n) {
      const float xv = sxT[j * 33 + tn * NPT + n];
      acc[n][0] = fmaf(xv, wv.x, acc[n][0]);
      acc[n][1] = fmaf(xv, wv.y, acc[n][1]);
      acc[n][2] = fmaf(xv, wv.z, acc[n][2]);
      acc[n][3] = fmaf(xv, wv.w, acc[n][3]);
    }
  }

  #pragma unroll
  for (int n = 0; n < NPT; ++n) {
    const long row = node0 + tn * NPT + n;
    float4 o = make_float4(acc[n][0], acc[n][1], acc[n][2], acc[n][3]);
    if constexpr (RELU) {
      o.x = fmaxf(o.x, 0.f); o.y = fmaxf(o.y, 0.f);
      o.z = fmaxf(o.z, 0.f); o.w = fmaxf(o.w, 0.f);
    }
    *(float4*)&Y[row * M + tf * 4] = o;
  }
}

// ---------------------------------------------------------------------------
// CSR build: histogram -> hierarchical scan -> fill
// ---------------------------------------------------------------------------
#define SCAN_NB ((N_ + 255) / 256)   // 391

__global__ __launch_bounds__(256) void k_zero(int* __restrict__ deg) {
  int i = blockIdx.x * 256 + threadIdx.x;
  if (i < N_) deg[i] = 0;
}

__global__ __launch_bounds__(256) void k_hist(const int* __restrict__ ei,
                                              int* __restrict__ deg) {
  int e = blockIdx.x * 256 + threadIdx.x;
  if (e < E_) atomicAdd(&deg[ei[E_ + e]], 1);
}

__global__ __launch_bounds__(256) void k_scan1(const int* __restrict__ deg,
                                               int* __restrict__ off,
                                               int* __restrict__ bsum) {
  __shared__ int s[256];
  const int t = threadIdx.x;
  const int i = blockIdx.x * 256 + t;
  const int v = (i < N_) ? deg[i] : 0;
  s[t] = v;
  __syncthreads();
  #pragma unroll
  for (int o = 1; o < 256; o <<= 1) {
    int u = (t >= o) ? s[t - o] : 0;
    __syncthreads();
    s[t] += u;
    __syncthreads();
  }
  if (i < N_) off[i] = s[t] - v;
  if (t == 255) bsum[blockIdx.x] = s[255];
}

__global__ __launch_bounds__(512) void k_scan2(int* __restrict__ bsum) {
  __shared__ int s[512];
  const int t = threadIdx.x;
  const int v = (t < SCAN_NB) ? bsum[t] : 0;
  s[t] = v;
  __syncthreads();
  #pragma unroll
  for (int o = 1; o < 512; o <<= 1) {
    int u = (t >= o) ? s[t - o] : 0;
    __syncthreads();
    s[t] += u;
    __syncthreads();
  }
  if (t < SCAN_NB) bsum[t] = s[t] - v;
}

__global__ __launch_bounds__(256) void k_scan3(int* __restrict__ off,
                                               const int* __restrict__ bsum,
                                               int* __restrict__ cur) {
  const int i = blockIdx.x * 256 + threadIdx.x;
  if (i < N_) {
    const int o = off[i] + bsum[blockIdx.x];
    off[i] = o;
    cur[i] = o;
  }
}

__global__ __launch_bounds__(256) void k_fill(const int* __restrict__ ei,
                                              int* __restrict__ cur,
                                              int* __restrict__ esrc) {
  int e = blockIdx.x * 256 + threadIdx.x;
  if (e < E_) {
    int src = ei[e], dst = ei[E_ + e];
    int pos = atomicAdd(&cur[dst], 1);
    esrc[pos] = src;
  }
}

// ---------------------------------------------------------------------------
// Flash-style attention aggregation: one wave per destination node,
// edge loop unrolled by 2 with a merged online-softmax update.
// ---------------------------------------------------------------------------
__global__ __launch_bounds__(256) void k_attn(
    const int* __restrict__ esrc, const int* __restrict__ off,
    const int* __restrict__ deg, const float* __restrict__ q,
    const float* __restrict__ kbuf, const float* __restrict__ vbuf,
    float* __restrict__ out)
{
  const int node = blockIdx.x * 4 + (threadIdx.x >> 6);
  const int lane = threadIdx.x & 63;
  if (node >= N_) return;

  const int start = off[node];
  const int cnt   = deg[node];
  const float scale = 0.17677669529663687f;  // 1/sqrt(32)

  const float q0 = q[(long)node * D_ + lane] * scale;
  const float q1 = q[(long)node * D_ + lane + 64] * scale;

  float m0 = -__builtin_inff(), l0 = 0.f, a0 = 0.f;
  float m1 = -__builtin_inff(), l1 = 0.f, a1 = 0.f;

  int i = start;
  const int end = start + cnt;

  for (; i + 1 < end; i += 2) {
    const int sa = esrc[i];
    const int sb = esrc[i + 1];
    const float ka0 = kbuf[(long)sa * D_ + lane];
    const float ka1 = kbuf[(long)sa * D_ + lane + 64];
    const float kb0 = kbuf[(long)sb * D_ + lane];
    const float kb1 = kbuf[(long)sb * D_ + lane + 64];
    const float va0 = vbuf[(long)sa * D_ + lane];
    const float va1 = vbuf[(long)sa * D_ + lane + 64];
    const float vb0 = vbuf[(long)sb * D_ + lane];
    const float vb1 = vbuf[(long)sb * D_ + lane + 64];

    float pa0 = q0 * ka0, pa1 = q1 * ka1;
    float pb0 = q0 * kb0, pb1 = q1 * kb1;
    #pragma unroll
    for (int msk = 16; msk >= 1; msk >>= 1) {
      pa0 += __shfl_xor(pa0, msk);
      pa1 += __shfl_xor(pa1, msk);
      pb0 += __shfl_xor(pb0, msk);
      pb1 += __shfl_xor(pb1, msk);
    }

    const float mn0 = fmaxf(m0, fmaxf(pa0, pb0));
    const float s0  = __expf(m0 - mn0);
    const float ea0 = __expf(pa0 - mn0);
    const float eb0 = __expf(pb0 - mn0);
    l0 = l0 * s0 + ea0 + eb0;
    a0 = a0 * s0 + ea0 * va0 + eb0 * vb0;
    m0 = mn0;

    const float mn1 = fmaxf(m1, fmaxf(pa1, pb1));
    const float s1  = __expf(m1 - mn1);
    const float ea1 = __expf(pa1 - mn1);
    const float eb1 = __expf(pb1 - mn1);
    l1 = l1 * s1 + ea1 + eb1;
    a1 = a1 * s1 + ea1 * va1 + eb1 * vb1;
    m1 = mn1;
  }

  if (i < end) {
    const int src = esrc[i];
    const float k0 = kbuf[(long)src * D_ + lane];
    const float k1 = kbuf[(long)src * D_ + lane + 64];
    const float v0 = vbuf[(long)src * D_ + lane];
    const float v1 = vbuf[(long)src * D_ + lane + 64];

    float p0 = q0 * k0;
    float p1 = q1 * k1;
    #pragma unroll
    for (int msk = 16; msk >= 1; msk >>= 1) {
      p0 += __shfl_xor(p0, msk);
      p1 += __shfl_xor(p1, msk);
    }

    const float m0n = fmaxf(m0, p0);
    const float sc0 = __expf(m0 - m0n);
    const float e0  = __expf(p0 - m0n);
    l0 = l0 * sc0 + e0;
    a0 = a0 * sc0 + e0 * v0;
    m0 = m0n;

    const float m1n = fmaxf(m1, p1);
    const float sc1 = __expf(m1 - m1n);
    const float e1  = __expf(p1 - m1n);
    l1 = l1 * sc1 + e1;
    a1 = a1 * sc1 + e1 * v1;
    m1 = m1n;
  }

  const float r0 = (l0 > 0.f) ? a0 / l0 : 0.f;
  const float r1 = (l1 > 0.f) ? a1 / l1 : 0.f;
  out[(long)node * D_ + lane]      += r0;
  out[(long)node * D_ + lane + 64] += r1;
}

// ---------------------------------------------------------------------------
extern "C" void kernel_launch(void* const* d_in, const int* in_sizes, int n_in,
                              void* d_out, int out_size, void* d_ws, size_t ws_size,
                              hipStream_t stream) {
  const float* x   = (const float*)d_in[0];
  const int*   ei  = (const int*)d_in[1];
  const float* pW1 = (const float*)d_in[2];  const float* pb1 = (const float*)d_in[3];
  const float* pW2 = (const float*)d_in[4];  const float* pb2 = (const float*)d_in[5];
  const float* pW3 = (const float*)d_in[6];  const float* pb3 = (const float*)d_in[7];
  const float* uW1 = (const float*)d_in[8];  const float* ub1 = (const float*)d_in[9];
  const float* uW2 = (const float*)d_in[10]; const float* ub2 = (const float*)d_in[11];
  const float* uW3 = (const float*)d_in[12]; const float* ub3 = (const float*)d_in[13];
  const float* qW  = (const float*)d_in[14]; const float* qb  = (const float*)d_in[15];
  const float* kW  = (const float*)d_in[16]; const float* kb  = (const float*)d_in[17];
  const float* vW  = (const float*)d_in[18]; const float* vb  = (const float*)d_in[19];
  const float* sW  = (const float*)d_in[20]; const float* sb  = (const float*)d_in[21];

  float* out = (float*)d_out;
  float* ws  = (float*)d_ws;

  const long ND = (long)N_ * D_;
  float* h_init = ws;           // region 0
  float* qbuf   = ws + ND;      // region 1
  float* kbuf   = ws + 2 * ND;  // region 2
  float* vbuf   = ws + 3 * ND;  // region 3

  // CSR overlays in region 0 (h_init dead after the projections)
  int* deg  = (int*)h_init;
  int* off  = deg + N_;
  int* cur  = off + N_;
  int* esrc = cur + N_;
  int* bsum = esrc + E_;

  // update-MLP temporaries (regions 1/2 dead after k_attn)
  float* t1 = kbuf;
  float* t2 = qbuf;

  const int g32 = N_ / NT_;            // 3125
  const int gT  = (N_ + 127) / 128;    // 782 (128-node MFMA tiles)

  // --- prep MLP: x -> h_init ---
  gemm_small<F_, 64, true><<<g32, 128, 0, stream>>>(x, pW1, pb1, t1);
  mfma_gemm<64, 128, true,  false><<<gT, 256, 0, stream>>>(t1, pW2, pb2, nullptr, t2);
  mfma_gemm<128,128, false, false><<<gT, 256, 0, stream>>>(t2, pW3, pb3, nullptr, h_init);

  // --- projections ---
  mfma_gemm<128,128, false, false><<<gT, 256, 0, stream>>>(h_init, qW, qb, nullptr, qbuf);
  mfma_gemm<128,128, false, false><<<gT, 256, 0, stream>>>(h_init, kW, kb, nullptr, kbuf);
  mfma_gemm<128,128, false, false><<<gT, 256, 0, stream>>>(h_init, vW, vb, nullptr, vbuf);
  mfma_gemm<128,128, false, false><<<gT, 256, 0, stream>>>(h_init, sW, sb, nullptr, out);

  // --- CSR build (region 0 now free) ---
  k_zero <<<(N_ + 255) / 256, 256, 0, stream>>>(deg);
  k_hist <<<(E_ + 255) / 256, 256, 0, stream>>>(ei, deg);
  k_scan1<<<SCAN_NB, 256, 0, stream>>>(deg, off, bsum);
  k_scan2<<<1, 512, 0, stream>>>(bsum);
  k_scan3<<<SCAN_NB, 256, 0, stream>>>(off, bsum, cur);
  k_fill <<<(E_ + 255) / 256, 256, 0, stream>>>(ei, cur, esrc);

  // --- attention (adds onto skip already in out) ---
  k_attn<<<(N_ + 3) / 4, 256, 0, stream>>>(esrc, off, deg, qbuf, kbuf, vbuf, out);

  // --- update MLP with residual: out = h + mlp(h), h == out ---
  mfma_gemm<128, 64, true,  false><<<gT, 256, 0, stream>>>(out, uW1, ub1, nullptr, t1);
  mfma_gemm<64, 128, true,  false><<<gT, 256, 0, stream>>>(t1,  uW2, ub2, nullptr, t2);
  mfma_gemm<128,128, false, true ><<<gT, 256, 0, stream>>>(t2,  uW3, ub3, out, out);
}

// Round 7
// 512.249 us; speedup vs baseline: 1.1571x; 1.1571x over previous
//
#include <hip/hip_runtime.h>
#include <hip/hip_bf16.h>

#define N_  100000
#define F_  5
#define D_  128
#define H_  4
#define HD_ 32
#define E_  800000
#define NT_ 32

typedef __attribute__((ext_vector_type(8))) short bf16x8;
typedef __attribute__((ext_vector_type(4))) float f32x4;

__device__ __forceinline__ unsigned short f2bf(float f) {
  unsigned u = __float_as_uint(f);
  u += 0x7FFF + ((u >> 16) & 1);          // round-to-nearest-even
  return (unsigned short)(u >> 16);
}

__device__ __forceinline__ unsigned pk2(float a, float b) {
  __hip_bfloat162 h = __float22bfloat162_rn(make_float2(a, b));  // v_cvt_pk_bf16_f32
  return *(unsigned*)&h;
}

// ---------------------------------------------------------------------------
// Weight pre-pass: W[k][m] (fp32) -> fragment-tiled bf16 WT.
// WT[((i*(K/8) + kq)*16 + l)*8 + r] = bf16(W[(kq*8+r)*M + i*16 + l])
// so a wave's A-fragment load (16 lanes x 16B) is 256B contiguous.
// ---------------------------------------------------------------------------
template<int K, int M>
__global__ __launch_bounds__(256) void k_wconv(const float* __restrict__ W,
                                               unsigned short* __restrict__ WT) {
  const int idx = blockIdx.x * 256 + threadIdx.x;
  if (idx >= K * M) return;
  const int r = idx & 7;
  const int l = (idx >> 3) & 15;
  const int rest = idx >> 7;
  const int kq = rest % (K / 8);
  const int i  = rest / (K / 8);
  WT[idx] = f2bf(W[(kq * 8 + r) * M + i * 16 + l]);
}

// ---------------------------------------------------------------------------
// MFMA GEMM over NW weight sets sharing one LDS-staged X tile.
// Tile: 128 nodes x M. 4 waves: wc=node-half, wr=feature-half.
// A = W^T fragments (coalesced 256B loads from WT, L2-resident),
// B = X fragments (ds_read_b128 from bf16 LDS tile).
// C/D: col(lane&15)=node, row=(lane>>4)*4+reg=feature -> float4 epilogue.
// ---------------------------------------------------------------------------
template<int K, int M, int NW, bool RELU, bool RES>
__global__ __launch_bounds__(256) void mfma_gemmN(
    const float* __restrict__ X,
    const unsigned short* __restrict__ wt0, const unsigned short* __restrict__ wt1,
    const unsigned short* __restrict__ wt2, const unsigned short* __restrict__ wt3,
    const float* __restrict__ b0, const float* __restrict__ b1,
    const float* __restrict__ b2, const float* __restrict__ b3,
    const float* __restrict__ Res,
    float* __restrict__ y0, float* __restrict__ y1,
    float* __restrict__ y2, float* __restrict__ y3)
{
  constexpr int SX = K + 8;      // LDS row stride (bf16); 16B-aligned, 4-bank skew
  constexpr int IF = M / 32;     // feature tiles per wave (4 or 2)

  __shared__ unsigned short sX[128 * SX];

  const int t = threadIdx.x;
  const int node0 = blockIdx.x * 128;
  const int lane = t & 63;
  const int w  = t >> 6;
  const int wr = w >> 1, wc = w & 1;
  const int l16 = lane & 15, kg = lane >> 4;

  // ---- stage X tile (coalesced fp32 float4 -> packed bf16 LDS) ----
  #pragma unroll
  for (int i = 0; i < (128 * K / 4) / 256; ++i) {
    const int g = t + 256 * i;
    const int row = g / (K / 4);
    const int kc  = g % (K / 4);
    const int node = node0 + row;
    float4 xv = (node < N_) ? ((const float4*)X)[(long)node * (K / 4) + kc]
                            : make_float4(0.f, 0.f, 0.f, 0.f);
    uint2 p;
    p.x = pk2(xv.x, xv.y);
    p.y = pk2(xv.z, xv.w);
    *(uint2*)&sX[row * SX + kc * 4] = p;
  }
  __syncthreads();

  const unsigned short* wts[4] = {wt0, wt1, wt2, wt3};
  const float* bs[4] = {b0, b1, b2, b3};
  float* ys[4] = {y0, y1, y2, y3};

  #pragma unroll
  for (int ws = 0; ws < NW; ++ws) {
    const unsigned short* __restrict__ WT = wts[ws];

    f32x4 acc[IF][4];
    #pragma unroll
    for (int i = 0; i < IF; ++i)
      #pragma unroll
      for (int j = 0; j < 4; ++j) acc[i][j] = (f32x4){0.f, 0.f, 0.f, 0.f};

    #pragma unroll
    for (int k0 = 0; k0 < K; k0 += 32) {
      const int kq = k0 / 8 + kg;
      bf16x8 aw[IF];
      #pragma unroll
      for (int i = 0; i < IF; ++i) {
        const int ti = wr * IF + i;
        aw[i] = *(const bf16x8*)&WT[((ti * (K / 8) + kq) * 16 + l16) * 8];
      }
      #pragma unroll
      for (int j = 0; j < 4; ++j) {
        const bf16x8 bx = *(const bf16x8*)&sX[(wc * 64 + j * 16 + l16) * SX + k0 + kg * 8];
        #pragma unroll
        for (int i = 0; i < IF; ++i)
          acc[i][j] = __builtin_amdgcn_mfma_f32_16x16x32_bf16(aw[i], bx, acc[i][j], 0, 0, 0);
      }
    }

    // ---- epilogue ----
    const float* __restrict__ bias = bs[ws];
    float* __restrict__ Y = ys[ws];
    float4 b4[IF];
    #pragma unroll
    for (int i = 0; i < IF; ++i)
      b4[i] = *(const float4*)&bias[(wr * IF + i) * 16 + kg * 4];

    #pragma unroll
    for (int j = 0; j < 4; ++j) {
      const int node = node0 + wc * 64 + j * 16 + l16;
      if (node >= N_) continue;
      #pragma unroll
      for (int i = 0; i < IF; ++i) {
        const int f0 = (wr * IF + i) * 16 + kg * 4;
        float4 o = make_float4(acc[i][j][0] + b4[i].x, acc[i][j][1] + b4[i].y,
                               acc[i][j][2] + b4[i].z, acc[i][j][3] + b4[i].w);
        if constexpr (RELU) {
          o.x = fmaxf(o.x, 0.f); o.y = fmaxf(o.y, 0.f);
          o.z = fmaxf(o.z, 0.f); o.w = fmaxf(o.w, 0.f);
        }
        if constexpr (RES) {
          const float4 r = *(const float4*)&Res[(long)node * M + f0];
          o.x += r.x; o.y += r.y; o.z += r.z; o.w += r.w;
        }
        *(float4*)&Y[(long)node * M + f0] = o;
      }
    }
  }
}

// ---------------------------------------------------------------------------
// Small-K GEMM (K=5), fp32.
// ---------------------------------------------------------------------------
template<int K, int M, bool RELU>
__global__ __launch_bounds__(128) void gemm_small(
    const float* __restrict__ X, const float* __restrict__ W,
    const float* __restrict__ bias, float* __restrict__ Y)
{
  constexpr int FG  = M / 4;
  constexpr int NG  = 128 / FG;
  constexpr int NPT = NT_ / NG;

  __shared__ float sxT[K * 33];
  __shared__ float sw[K * M];
  __shared__ float sb[M];

  const int t = threadIdx.x;
  const long node0 = (long)blockIdx.x * NT_;

  for (int i = t; i < NT_ * K; i += 128) {
    int n = i / K, k = i % K;
    sxT[k * 33 + n] = X[(node0 + n) * K + k];
  }
  for (int i = t; i < K * M; i += 128) sw[i] = W[i];
  if (t < M) sb[t] = bias[t];
  __syncthreads();

  const int tf = t % FG;
  const int tn = t / FG;
  float acc[NPT][4];
  #pragma unroll
  for (int n = 0; n < NPT; ++n)
    #pragma unroll
    for (int f = 0; f < 4; ++f) acc[n][f] = sb[tf * 4 + f];

  #pragma unroll
  for (int j = 0; j < K; ++j) {
    const float4 wv = *(const float4*)&sw[j * M + tf * 4];
    #pragma unroll
    for (int n = 0; n < NPT; ++n) {
      const float xv = sxT[j * 33 + tn * NPT + n];
      acc[n][0] = fmaf(xv, wv.x, acc[n][0]);
      acc[n][1] = fmaf(xv, wv.y, acc[n][1]);
      acc[n][2] = fmaf(xv, wv.z, acc[n][2]);
      acc[n][3] = fmaf(xv, wv.w, acc[n][3]);
    }
  }

  #pragma unroll
  for (int n = 0; n < NPT; ++n) {
    const long row = node0 + tn * NPT + n;
    float4 o = make_float4(acc[n][0], acc[n][1], acc[n][2], acc[n][3]);
    if constexpr (RELU) {
      o.x = fmaxf(o.x, 0.f); o.y = fmaxf(o.y, 0.f);
      o.z = fmaxf(o.z, 0.f); o.w = fmaxf(o.w, 0.f);
    }
    *(float4*)&Y[row * M + tf * 4] = o;
  }
}

// ---------------------------------------------------------------------------
// CSR build: histogram -> hierarchical scan -> fill
// ---------------------------------------------------------------------------
#define SCAN_NB ((N_ + 255) / 256)   // 391

__global__ __launch_bounds__(256) void k_zero(int* __restrict__ deg) {
  int i = blockIdx.x * 256 + threadIdx.x;
  if (i < N_) deg[i] = 0;
}

__global__ __launch_bounds__(256) void k_hist(const int* __restrict__ ei,
                                              int* __restrict__ deg) {
  int e = blockIdx.x * 256 + threadIdx.x;
  if (e < E_) atomicAdd(&deg[ei[E_ + e]], 1);
}

__global__ __launch_bounds__(256) void k_scan1(const int* __restrict__ deg,
                                               int* __restrict__ off,
                                               int* __restrict__ bsum) {
  __shared__ int s[256];
  const int t = threadIdx.x;
  const int i = blockIdx.x * 256 + t;
  const int v = (i < N_) ? deg[i] : 0;
  s[t] = v;
  __syncthreads();
  #pragma unroll
  for (int o = 1; o < 256; o <<= 1) {
    int u = (t >= o) ? s[t - o] : 0;
    __syncthreads();
    s[t] += u;
    __syncthreads();
  }
  if (i < N_) off[i] = s[t] - v;
  if (t == 255) bsum[blockIdx.x] = s[255];
}

__global__ __launch_bounds__(512) void k_scan2(int* __restrict__ bsum) {
  __shared__ int s[512];
  const int t = threadIdx.x;
  const int v = (t < SCAN_NB) ? bsum[t] : 0;
  s[t] = v;
  __syncthreads();
  #pragma unroll
  for (int o = 1; o < 512; o <<= 1) {
    int u = (t >= o) ? s[t - o] : 0;
    __syncthreads();
    s[t] += u;
    __syncthreads();
  }
  if (t < SCAN_NB) bsum[t] = s[t] - v;
}

__global__ __launch_bounds__(256) void k_scan3(int* __restrict__ off,
                                               const int* __restrict__ bsum,
                                               int* __restrict__ cur) {
  const int i = blockIdx.x * 256 + threadIdx.x;
  if (i < N_) {
    const int o = off[i] + bsum[blockIdx.x];
    off[i] = o;
    cur[i] = o;
  }
}

__global__ __launch_bounds__(256) void k_fill(const int* __restrict__ ei,
                                              int* __restrict__ cur,
                                              int* __restrict__ esrc) {
  int e = blockIdx.x * 256 + threadIdx.x;
  if (e < E_) {
    int src = ei[e], dst = ei[E_ + e];
    int pos = atomicAdd(&cur[dst], 1);
    esrc[pos] = src;
  }
}

// ---------------------------------------------------------------------------
// Flash-style attention aggregation: one wave per destination node,
// edge loop unrolled by 2 with a merged online-softmax update.
// ---------------------------------------------------------------------------
__global__ __launch_bounds__(256) void k_attn(
    const int* __restrict__ esrc, const int* __restrict__ off,
    const int* __restrict__ deg, const float* __restrict__ q,
    const float* __restrict__ kbuf, const float* __restrict__ vbuf,
    float* __restrict__ out)
{
  const int node = blockIdx.x * 4 + (threadIdx.x >> 6);
  const int lane = threadIdx.x & 63;
  if (node >= N_) return;

  const int start = off[node];
  const int cnt   = deg[node];
  const float scale = 0.17677669529663687f;  // 1/sqrt(32)

  const float q0 = q[(long)node * D_ + lane] * scale;
  const float q1 = q[(long)node * D_ + lane + 64] * scale;

  float m0 = -__builtin_inff(), l0 = 0.f, a0 = 0.f;
  float m1 = -__builtin_inff(), l1 = 0.f, a1 = 0.f;

  int i = start;
  const int end = start + cnt;

  for (; i + 1 < end; i += 2) {
    const int sa = esrc[i];
    const int sb = esrc[i + 1];
    const float ka0 = kbuf[(long)sa * D_ + lane];
    const float ka1 = kbuf[(long)sa * D_ + lane + 64];
    const float kb0 = kbuf[(long)sb * D_ + lane];
    const float kb1 = kbuf[(long)sb * D_ + lane + 64];
    const float va0 = vbuf[(long)sa * D_ + lane];
    const float va1 = vbuf[(long)sa * D_ + lane + 64];
    const float vb0 = vbuf[(long)sb * D_ + lane];
    const float vb1 = vbuf[(long)sb * D_ + lane + 64];

    float pa0 = q0 * ka0, pa1 = q1 * ka1;
    float pb0 = q0 * kb0, pb1 = q1 * kb1;
    #pragma unroll
    for (int msk = 16; msk >= 1; msk >>= 1) {
      pa0 += __shfl_xor(pa0, msk);
      pa1 += __shfl_xor(pa1, msk);
      pb0 += __shfl_xor(pb0, msk);
      pb1 += __shfl_xor(pb1, msk);
    }

    const float mn0 = fmaxf(m0, fmaxf(pa0, pb0));
    const float s0  = __expf(m0 - mn0);
    const float ea0 = __expf(pa0 - mn0);
    const float eb0 = __expf(pb0 - mn0);
    l0 = l0 * s0 + ea0 + eb0;
    a0 = a0 * s0 + ea0 * va0 + eb0 * vb0;
    m0 = mn0;

    const float mn1 = fmaxf(m1, fmaxf(pa1, pb1));
    const float s1  = __expf(m1 - mn1);
    const float ea1 = __expf(pa1 - mn1);
    const float eb1 = __expf(pb1 - mn1);
    l1 = l1 * s1 + ea1 + eb1;
    a1 = a1 * s1 + ea1 * va1 + eb1 * vb1;
    m1 = mn1;
  }

  if (i < end) {
    const int src = esrc[i];
    const float k0 = kbuf[(long)src * D_ + lane];
    const float k1 = kbuf[(long)src * D_ + lane + 64];
    const float v0 = vbuf[(long)src * D_ + lane];
    const float v1 = vbuf[(long)src * D_ + lane + 64];

    float p0 = q0 * k0;
    float p1 = q1 * k1;
    #pragma unroll
    for (int msk = 16; msk >= 1; msk >>= 1) {
      p0 += __shfl_xor(p0, msk);
      p1 += __shfl_xor(p1, msk);
    }

    const float m0n = fmaxf(m0, p0);
    const float sc0 = __expf(m0 - m0n);
    const float e0  = __expf(p0 - m0n);
    l0 = l0 * sc0 + e0;
    a0 = a0 * sc0 + e0 * v0;
    m0 = m0n;

    const float m1n = fmaxf(m1, p1);
    const float sc1 = __expf(m1 - m1n);
    const float e1  = __expf(p1 - m1n);
    l1 = l1 * sc1 + e1;
    a1 = a1 * sc1 + e1 * v1;
    m1 = m1n;
  }

  const float r0 = (l0 > 0.f) ? a0 / l0 : 0.f;
  const float r1 = (l1 > 0.f) ? a1 / l1 : 0.f;
  out[(long)node * D_ + lane]      += r0;
  out[(long)node * D_ + lane + 64] += r1;
}

// ---------------------------------------------------------------------------
extern "C" void kernel_launch(void* const* d_in, const int* in_sizes, int n_in,
                              void* d_out, int out_size, void* d_ws, size_t ws_size,
                              hipStream_t stream) {
  const float* x   = (const float*)d_in[0];
  const int*   ei  = (const int*)d_in[1];
  const float* pW1 = (const float*)d_in[2];  const float* pb1 = (const float*)d_in[3];
  const float* pW2 = (const float*)d_in[4];  const float* pb2 = (const float*)d_in[5];
  const float* pW3 = (const float*)d_in[6];  const float* pb3 = (const float*)d_in[7];
  const float* uW1 = (const float*)d_in[8];  const float* ub1 = (const float*)d_in[9];
  const float* uW2 = (const float*)d_in[10]; const float* ub2 = (const float*)d_in[11];
  const float* uW3 = (const float*)d_in[12]; const float* ub3 = (const float*)d_in[13];
  const float* qW  = (const float*)d_in[14]; const float* qb  = (const float*)d_in[15];
  const float* kW  = (const float*)d_in[16]; const float* kb  = (const float*)d_in[17];
  const float* vW  = (const float*)d_in[18]; const float* vb  = (const float*)d_in[19];
  const float* sW  = (const float*)d_in[20]; const float* sb  = (const float*)d_in[21];

  float* out = (float*)d_out;
  float* ws  = (float*)d_ws;

  const long ND = (long)N_ * D_;
  float* h_init = ws;           // region 0
  float* qbuf   = ws + ND;      // region 1
  float* kbuf   = ws + 2 * ND;  // region 2
  float* vbuf   = ws + 3 * ND;  // region 3

  // bf16 fragment-tiled weights (region 4, ~246 KB)
  unsigned short* wtb = (unsigned short*)(ws + 4 * ND);
  unsigned short* wt_p2 = wtb;            // 64x128
  unsigned short* wt_p3 = wtb + 8192;     // 128x128
  unsigned short* wt_q  = wtb + 24576;
  unsigned short* wt_k  = wtb + 40960;
  unsigned short* wt_v  = wtb + 57344;
  unsigned short* wt_s  = wtb + 73728;
  unsigned short* wt_u1 = wtb + 90112;    // 128x64
  unsigned short* wt_u2 = wtb + 98304;    // 64x128
  unsigned short* wt_u3 = wtb + 106496;   // 128x128

  // CSR overlays in region 0 (h_init dead after the projections)
  int* deg  = (int*)h_init;
  int* off  = deg + N_;
  int* cur  = off + N_;
  int* esrc = cur + N_;
  int* bsum = esrc + E_;

  // update-MLP temporaries (regions 1/2 dead after k_attn)
  float* t1 = kbuf;
  float* t2 = qbuf;

  const int g32 = N_ / NT_;            // 3125
  const int gT  = (N_ + 127) / 128;    // 782

  // --- weight pre-pass (bf16, fragment-tiled) ---
  k_wconv<64, 128><<<32, 256, 0, stream>>>(pW2, wt_p2);
  k_wconv<128,128><<<64, 256, 0, stream>>>(pW3, wt_p3);
  k_wconv<128,128><<<64, 256, 0, stream>>>(qW,  wt_q);
  k_wconv<128,128><<<64, 256, 0, stream>>>(kW,  wt_k);
  k_wconv<128,128><<<64, 256, 0, stream>>>(vW,  wt_v);
  k_wconv<128,128><<<64, 256, 0, stream>>>(sW,  wt_s);
  k_wconv<128, 64><<<32, 256, 0, stream>>>(uW1, wt_u1);
  k_wconv<64, 128><<<32, 256, 0, stream>>>(uW2, wt_u2);
  k_wconv<128,128><<<64, 256, 0, stream>>>(uW3, wt_u3);

  // --- prep MLP: x -> h_init ---
  gemm_small<F_, 64, true><<<g32, 128, 0, stream>>>(x, pW1, pb1, t1);
  mfma_gemmN<64, 128, 1, true,  false><<<gT, 256, 0, stream>>>(
      t1, wt_p2, nullptr, nullptr, nullptr, pb2, nullptr, nullptr, nullptr,
      nullptr, t2, nullptr, nullptr, nullptr);
  mfma_gemmN<128, 128, 1, false, false><<<gT, 256, 0, stream>>>(
      t2, wt_p3, nullptr, nullptr, nullptr, pb3, nullptr, nullptr, nullptr,
      nullptr, h_init, nullptr, nullptr, nullptr);

  // --- fused projections: h_init -> q,k,v,skip(out) ---
  mfma_gemmN<128, 128, 4, false, false><<<gT, 256, 0, stream>>>(
      h_init, wt_q, wt_k, wt_v, wt_s, qb, kb, vb, sb,
      nullptr, qbuf, kbuf, vbuf, out);

  // --- CSR build (region 0 now free) ---
  k_zero <<<(N_ + 255) / 256, 256, 0, stream>>>(deg);
  k_hist <<<(E_ + 255) / 256, 256, 0, stream>>>(ei, deg);
  k_scan1<<<SCAN_NB, 256, 0, stream>>>(deg, off, bsum);
  k_scan2<<<1, 512, 0, stream>>>(bsum);
  k_scan3<<<SCAN_NB, 256, 0, stream>>>(off, bsum, cur);
  k_fill <<<(E_ + 255) / 256, 256, 0, stream>>>(ei, cur, esrc);

  // --- attention (adds onto skip already in out) ---
  k_attn<<<(N_ + 3) / 4, 256, 0, stream>>>(esrc, off, deg, qbuf, kbuf, vbuf, out);

  // --- update MLP with residual: out = h + mlp(h), h == out ---
  mfma_gemmN<128, 64, 1, true,  false><<<gT, 256, 0, stream>>>(
      out, wt_u1, nullptr, nullptr, nullptr, ub1, nullptr, nullptr, nullptr,
      nullptr, t1, nullptr, nullptr, nullptr);
  mfma_gemmN<64, 128, 1, true,  false><<<gT, 256, 0, stream>>>(
      t1, wt_u2, nullptr, nullptr, nullptr, ub2, nullptr, nullptr, nullptr,
      nullptr, t2, nullptr, nullptr, nullptr);
  mfma_gemmN<128, 128, 1, false, true><<<gT, 256, 0, stream>>>(
      t2, wt_u3, nullptr, nullptr, nullptr, ub3, nullptr, nullptr, nullptr,
      out, out, nullptr, nullptr, nullptr);
}

// Round 8
// 434.828 us; speedup vs baseline: 1.3631x; 1.1780x over previous
//
#include <hip/hip_runtime.h>
#include <hip/hip_bf16.h>

#define N_  100000
#define F_  5
#define D_  128
#define H_  4
#define HD_ 32
#define E_  800000
#define NT_ 32

typedef __attribute__((ext_vector_type(8))) short bf16x8;
typedef __attribute__((ext_vector_type(4))) float f32x4;

__device__ __forceinline__ unsigned short f2bf(float f) {
  unsigned u = __float_as_uint(f);
  u += 0x7FFF + ((u >> 16) & 1);          // round-to-nearest-even
  return (unsigned short)(u >> 16);
}

__device__ __forceinline__ unsigned pk2(float a, float b) {
  __hip_bfloat162 h = __float22bfloat162_rn(make_float2(a, b));  // v_cvt_pk_bf16_f32
  return *(unsigned*)&h;
}

__device__ __forceinline__ float2 bf2f2(unsigned u) {
  float2 r;
  r.x = __uint_as_float(u << 16);
  r.y = __uint_as_float(u & 0xffff0000u);
  return r;
}

// ---------------------------------------------------------------------------
// Weight pre-pass: W[k][m] (fp32) -> fragment-tiled bf16 WT.
// ---------------------------------------------------------------------------
template<int K, int M>
__global__ __launch_bounds__(256) void k_wconv(const float* __restrict__ W,
                                               unsigned short* __restrict__ WT) {
  const int idx = blockIdx.x * 256 + threadIdx.x;
  if (idx >= K * M) return;
  const int r = idx & 7;
  const int l = (idx >> 3) & 15;
  const int rest = idx >> 7;
  const int kq = rest % (K / 8);
  const int i  = rest / (K / 8);
  WT[idx] = f2bf(W[(kq * 8 + r) * M + i * 16 + l]);
}

// ---------------------------------------------------------------------------
// MFMA GEMM over NW weight sets sharing one LDS-staged X tile.
// INBF: input tensor already bf16 (pure copy staging). OMASK bit ws: output
// stored bf16 (else fp32). RES only used with fp32 output.
// ---------------------------------------------------------------------------
template<int K, int M, int NW, bool RELU, bool RES, bool INBF, int OMASK>
__global__ __launch_bounds__(256) void mfma_gemmN(
    const void* __restrict__ Xv,
    const unsigned short* __restrict__ wt0, const unsigned short* __restrict__ wt1,
    const unsigned short* __restrict__ wt2, const unsigned short* __restrict__ wt3,
    const float* __restrict__ b0, const float* __restrict__ b1,
    const float* __restrict__ b2, const float* __restrict__ b3,
    const float* __restrict__ Res,
    void* __restrict__ y0, void* __restrict__ y1,
    void* __restrict__ y2, void* __restrict__ y3)
{
  constexpr int SX = K + 8;      // LDS row stride (bf16)
  constexpr int IF = M / 32;     // feature tiles per wave (4 or 2)

  __shared__ unsigned short sX[128 * SX];

  const int t = threadIdx.x;
  const int node0 = blockIdx.x * 128;
  const int lane = t & 63;
  const int w  = t >> 6;
  const int wr = w >> 1, wc = w & 1;
  const int l16 = lane & 15, kg = lane >> 4;

  // ---- stage X tile into bf16 LDS ----
  if constexpr (INBF) {
    const unsigned short* X = (const unsigned short*)Xv;
    constexpr int CPR = K / 8;   // 16B chunks per row
    #pragma unroll
    for (int i = 0; i < (128 * CPR) / 256; ++i) {
      const int g = t + 256 * i;
      const int row = g / CPR, c = g % CPR;
      const int node = node0 + row;
      uint4 v = make_uint4(0u, 0u, 0u, 0u);
      if (node < N_) v = *(const uint4*)&X[(long)node * K + c * 8];
      *(uint4*)&sX[row * SX + c * 8] = v;
    }
  } else {
    const float* X = (const float*)Xv;
    #pragma unroll
    for (int i = 0; i < (128 * K / 4) / 256; ++i) {
      const int g = t + 256 * i;
      const int row = g / (K / 4);
      const int kc  = g % (K / 4);
      const int node = node0 + row;
      float4 xv = (node < N_) ? ((const float4*)X)[(long)node * (K / 4) + kc]
                              : make_float4(0.f, 0.f, 0.f, 0.f);
      uint2 p;
      p.x = pk2(xv.x, xv.y);
      p.y = pk2(xv.z, xv.w);
      *(uint2*)&sX[row * SX + kc * 4] = p;
    }
  }
  __syncthreads();

  const unsigned short* wts[4] = {wt0, wt1, wt2, wt3};
  const float* bs[4] = {b0, b1, b2, b3};
  void* ys[4] = {y0, y1, y2, y3};

  #pragma unroll
  for (int ws = 0; ws < NW; ++ws) {
    const unsigned short* __restrict__ WT = wts[ws];

    f32x4 acc[IF][4];
    #pragma unroll
    for (int i = 0; i < IF; ++i)
      #pragma unroll
      for (int j = 0; j < 4; ++j) acc[i][j] = (f32x4){0.f, 0.f, 0.f, 0.f};

    #pragma unroll
    for (int k0 = 0; k0 < K; k0 += 32) {
      const int kq = k0 / 8 + kg;
      bf16x8 aw[IF];
      #pragma unroll
      for (int i = 0; i < IF; ++i) {
        const int ti = wr * IF + i;
        aw[i] = *(const bf16x8*)&WT[((ti * (K / 8) + kq) * 16 + l16) * 8];
      }
      #pragma unroll
      for (int j = 0; j < 4; ++j) {
        const bf16x8 bx = *(const bf16x8*)&sX[(wc * 64 + j * 16 + l16) * SX + k0 + kg * 8];
        #pragma unroll
        for (int i = 0; i < IF; ++i)
          acc[i][j] = __builtin_amdgcn_mfma_f32_16x16x32_bf16(aw[i], bx, acc[i][j], 0, 0, 0);
      }
    }

    // ---- epilogue ----
    const float* __restrict__ bias = bs[ws];
    const bool obf = (OMASK >> ws) & 1;
    float4 b4[IF];
    #pragma unroll
    for (int i = 0; i < IF; ++i)
      b4[i] = *(const float4*)&bias[(wr * IF + i) * 16 + kg * 4];

    #pragma unroll
    for (int j = 0; j < 4; ++j) {
      const int node = node0 + wc * 64 + j * 16 + l16;
      if (node >= N_) continue;
      #pragma unroll
      for (int i = 0; i < IF; ++i) {
        const int f0 = (wr * IF + i) * 16 + kg * 4;
        float4 o = make_float4(acc[i][j][0] + b4[i].x, acc[i][j][1] + b4[i].y,
                               acc[i][j][2] + b4[i].z, acc[i][j][3] + b4[i].w);
        if constexpr (RELU) {
          o.x = fmaxf(o.x, 0.f); o.y = fmaxf(o.y, 0.f);
          o.z = fmaxf(o.z, 0.f); o.w = fmaxf(o.w, 0.f);
        }
        if (obf) {
          unsigned short* Yb = (unsigned short*)ys[ws];
          uint2 ob;
          ob.x = pk2(o.x, o.y);
          ob.y = pk2(o.z, o.w);
          *(uint2*)&Yb[(long)node * M + f0] = ob;
        } else {
          float* Yf = (float*)ys[ws];
          if constexpr (RES) {
            const float4 r = *(const float4*)&Res[(long)node * M + f0];
            o.x += r.x; o.y += r.y; o.z += r.z; o.w += r.w;
          }
          *(float4*)&Yf[(long)node * M + f0] = o;
        }
      }
    }
  }
}

// ---------------------------------------------------------------------------
// Small-K GEMM (K=5), fp32 in -> bf16 out.
// ---------------------------------------------------------------------------
template<int K, int M, bool RELU>
__global__ __launch_bounds__(128) void gemm_small(
    const float* __restrict__ X, const float* __restrict__ W,
    const float* __restrict__ bias, unsigned short* __restrict__ Y)
{
  constexpr int FG  = M / 4;
  constexpr int NG  = 128 / FG;
  constexpr int NPT = NT_ / NG;

  __shared__ float sxT[K * 33];
  __shared__ float sw[K * M];
  __shared__ float sb[M];

  const int t = threadIdx.x;
  const long node0 = (long)blockIdx.x * NT_;

  for (int i = t; i < NT_ * K; i += 128) {
    int n = i / K, k = i % K;
    sxT[k * 33 + n] = X[(node0 + n) * K + k];
  }
  for (int i = t; i < K * M; i += 128) sw[i] = W[i];
  if (t < M) sb[t] = bias[t];
  __syncthreads();

  const int tf = t % FG;
  const int tn = t / FG;
  float acc[NPT][4];
  #pragma unroll
  for (int n = 0; n < NPT; ++n)
    #pragma unroll
    for (int f = 0; f < 4; ++f) acc[n][f] = sb[tf * 4 + f];

  #pragma unroll
  for (int j = 0; j < K; ++j) {
    const float4 wv = *(const float4*)&sw[j * M + tf * 4];
    #pragma unroll
    for (int n = 0; n < NPT; ++n) {
      const float xv = sxT[j * 33 + tn * NPT + n];
      acc[n][0] = fmaf(xv, wv.x, acc[n][0]);
      acc[n][1] = fmaf(xv, wv.y, acc[n][1]);
      acc[n][2] = fmaf(xv, wv.z, acc[n][2]);
      acc[n][3] = fmaf(xv, wv.w, acc[n][3]);
    }
  }

  #pragma unroll
  for (int n = 0; n < NPT; ++n) {
    const long row = node0 + tn * NPT + n;
    float ox = acc[n][0], oy = acc[n][1], oz = acc[n][2], ow = acc[n][3];
    if constexpr (RELU) {
      ox = fmaxf(ox, 0.f); oy = fmaxf(oy, 0.f);
      oz = fmaxf(oz, 0.f); ow = fmaxf(ow, 0.f);
    }
    uint2 o;
    o.x = pk2(ox, oy);
    o.y = pk2(oz, ow);
    *(uint2*)&Y[row * M + tf * 4] = o;
  }
}

// ---------------------------------------------------------------------------
// CSR build: histogram -> hierarchical scan -> fill
// ---------------------------------------------------------------------------
#define SCAN_NB ((N_ + 255) / 256)   // 391

__global__ __launch_bounds__(256) void k_zero(int* __restrict__ deg) {
  int i = blockIdx.x * 256 + threadIdx.x;
  if (i < N_) deg[i] = 0;
}

__global__ __launch_bounds__(256) void k_hist(const int* __restrict__ ei,
                                              int* __restrict__ deg) {
  int e = blockIdx.x * 256 + threadIdx.x;
  if (e < E_) atomicAdd(&deg[ei[E_ + e]], 1);
}

__global__ __launch_bounds__(256) void k_scan1(const int* __restrict__ deg,
                                               int* __restrict__ off,
                                               int* __restrict__ bsum) {
  __shared__ int s[256];
  const int t = threadIdx.x;
  const int i = blockIdx.x * 256 + t;
  const int v = (i < N_) ? deg[i] : 0;
  s[t] = v;
  __syncthreads();
  #pragma unroll
  for (int o = 1; o < 256; o <<= 1) {
    int u = (t >= o) ? s[t - o] : 0;
    __syncthreads();
    s[t] += u;
    __syncthreads();
  }
  if (i < N_) off[i] = s[t] - v;
  if (t == 255) bsum[blockIdx.x] = s[255];
}

__global__ __launch_bounds__(512) void k_scan2(int* __restrict__ bsum) {
  __shared__ int s[512];
  const int t = threadIdx.x;
  const int v = (t < SCAN_NB) ? bsum[t] : 0;
  s[t] = v;
  __syncthreads();
  #pragma unroll
  for (int o = 1; o < 512; o <<= 1) {
    int u = (t >= o) ? s[t - o] : 0;
    __syncthreads();
    s[t] += u;
    __syncthreads();
  }
  if (t < SCAN_NB) bsum[t] = s[t] - v;
}

__global__ __launch_bounds__(256) void k_scan3(int* __restrict__ off,
                                               const int* __restrict__ bsum,
                                               int* __restrict__ cur) {
  const int i = blockIdx.x * 256 + threadIdx.x;
  if (i < N_) {
    const int o = off[i] + bsum[blockIdx.x];
    off[i] = o;
    cur[i] = o;
  }
}

__global__ __launch_bounds__(256) void k_fill(const int* __restrict__ ei,
                                              int* __restrict__ cur,
                                              int* __restrict__ esrc) {
  int e = blockIdx.x * 256 + threadIdx.x;
  if (e < E_) {
    int src = ei[e], dst = ei[E_ + e];
    int pos = atomicAdd(&cur[dst], 1);
    esrc[pos] = src;
  }
}

// ---------------------------------------------------------------------------
// Flash-style attention aggregation (bf16 q/k/v): one wave per destination
// node. Lane owns channels 2*lane, 2*lane+1 -> head = lane>>4; score reduce
// is 4 shfl_xor steps within 16-lane groups. Unrolled by 2.
// ---------------------------------------------------------------------------
__global__ __launch_bounds__(256) void k_attn(
    const int* __restrict__ esrc, const int* __restrict__ off,
    const int* __restrict__ deg,
    const unsigned short* __restrict__ q,
    const unsigned short* __restrict__ kbuf,
    const unsigned short* __restrict__ vbuf,
    float* __restrict__ out)
{
  const int node = blockIdx.x * 4 + (threadIdx.x >> 6);
  const int lane = threadIdx.x & 63;
  if (node >= N_) return;

  const int start = off[node];
  const int cnt   = deg[node];
  const float scale = 0.17677669529663687f;  // 1/sqrt(32)

  const float2 qv = bf2f2(*(const unsigned*)&q[(long)node * D_ + 2 * lane]);
  const float qx = qv.x * scale, qy = qv.y * scale;

  float m = -__builtin_inff(), l = 0.f, a0 = 0.f, a1 = 0.f;

  int i = start;
  const int end = start + cnt;

  for (; i + 1 < end; i += 2) {
    const int sa = esrc[i];
    const int sb = esrc[i + 1];
    const unsigned kua = *(const unsigned*)&kbuf[(long)sa * D_ + 2 * lane];
    const unsigned kub = *(const unsigned*)&kbuf[(long)sb * D_ + 2 * lane];
    const unsigned vua = *(const unsigned*)&vbuf[(long)sa * D_ + 2 * lane];
    const unsigned vub = *(const unsigned*)&vbuf[(long)sb * D_ + 2 * lane];

    const float2 ka = bf2f2(kua);
    const float2 kb = bf2f2(kub);
    float pa = qx * ka.x + qy * ka.y;
    float pb = qx * kb.x + qy * kb.y;
    #pragma unroll
    for (int msk = 8; msk >= 1; msk >>= 1) {
      pa += __shfl_xor(pa, msk);
      pb += __shfl_xor(pb, msk);
    }

    const float2 va = bf2f2(vua);
    const float2 vb = bf2f2(vub);
    const float mn = fmaxf(m, fmaxf(pa, pb));
    const float s  = __expf(m - mn);
    const float ea = __expf(pa - mn);
    const float eb = __expf(pb - mn);
    l  = l * s + ea + eb;
    a0 = a0 * s + ea * va.x + eb * vb.x;
    a1 = a1 * s + ea * va.y + eb * vb.y;
    m = mn;
  }

  if (i < end) {
    const int src = esrc[i];
    const unsigned ku = *(const unsigned*)&kbuf[(long)src * D_ + 2 * lane];
    const unsigned vu = *(const unsigned*)&vbuf[(long)src * D_ + 2 * lane];
    const float2 kf = bf2f2(ku);
    float p = qx * kf.x + qy * kf.y;
    #pragma unroll
    for (int msk = 8; msk >= 1; msk >>= 1) p += __shfl_xor(p, msk);

    const float2 vf = bf2f2(vu);
    const float mn = fmaxf(m, p);
    const float s  = __expf(m - mn);
    const float e  = __expf(p - mn);
    l  = l * s + e;
    a0 = a0 * s + e * vf.x;
    a1 = a1 * s + e * vf.y;
    m = mn;
  }

  const float r0 = (l > 0.f) ? a0 / l : 0.f;
  const float r1 = (l > 0.f) ? a1 / l : 0.f;
  float2* op = (float2*)&out[(long)node * D_ + 2 * lane];
  float2 cv = *op;
  cv.x += r0;
  cv.y += r1;
  *op = cv;
}

// ---------------------------------------------------------------------------
extern "C" void kernel_launch(void* const* d_in, const int* in_sizes, int n_in,
                              void* d_out, int out_size, void* d_ws, size_t ws_size,
                              hipStream_t stream) {
  const float* x   = (const float*)d_in[0];
  const int*   ei  = (const int*)d_in[1];
  const float* pW1 = (const float*)d_in[2];  const float* pb1 = (const float*)d_in[3];
  const float* pW2 = (const float*)d_in[4];  const float* pb2 = (const float*)d_in[5];
  const float* pW3 = (const float*)d_in[6];  const float* pb3 = (const float*)d_in[7];
  const float* uW1 = (const float*)d_in[8];  const float* ub1 = (const float*)d_in[9];
  const float* uW2 = (const float*)d_in[10]; const float* ub2 = (const float*)d_in[11];
  const float* uW3 = (const float*)d_in[12]; const float* ub3 = (const float*)d_in[13];
  const float* qW  = (const float*)d_in[14]; const float* qb  = (const float*)d_in[15];
  const float* kW  = (const float*)d_in[16]; const float* kb  = (const float*)d_in[17];
  const float* vW  = (const float*)d_in[18]; const float* vb  = (const float*)d_in[19];
  const float* sW  = (const float*)d_in[20]; const float* sb  = (const float*)d_in[21];

  float* out = (float*)d_out;
  float* ws  = (float*)d_ws;

  const long ND = (long)N_ * D_;
  // regions (each ND floats): 0=h_init(bf16)+CSR overlay, 1=q, 2=k, 3=v
  unsigned short* h16 = (unsigned short*)ws;
  unsigned short* q16 = (unsigned short*)(ws + ND);
  unsigned short* k16 = (unsigned short*)(ws + 2 * ND);
  unsigned short* v16 = (unsigned short*)(ws + 3 * ND);

  // bf16 fragment-tiled weights (region 4, ~246 KB)
  unsigned short* wtb = (unsigned short*)(ws + 4 * ND);
  unsigned short* wt_p2 = wtb;            // 64x128
  unsigned short* wt_p3 = wtb + 8192;     // 128x128
  unsigned short* wt_q  = wtb + 24576;
  unsigned short* wt_k  = wtb + 40960;
  unsigned short* wt_v  = wtb + 57344;
  unsigned short* wt_s  = wtb + 73728;
  unsigned short* wt_u1 = wtb + 90112;    // 128x64
  unsigned short* wt_u2 = wtb + 98304;    // 64x128
  unsigned short* wt_u3 = wtb + 106496;   // 128x128

  // CSR overlays in region 0 (h16 dead after the fused projections)
  int* deg  = (int*)ws;
  int* off  = deg + N_;
  int* cur  = off + N_;
  int* esrc = cur + N_;
  int* bsum = esrc + E_;

  // MLP temporaries (regions 1/2 reused: dead before q/k written, dead after attn)
  unsigned short* t1b = k16;
  unsigned short* t2b = q16;

  const int g32 = N_ / NT_;            // 3125
  const int gT  = (N_ + 127) / 128;    // 782

  // --- weight pre-pass (bf16, fragment-tiled) ---
  k_wconv<64, 128><<<32, 256, 0, stream>>>(pW2, wt_p2);
  k_wconv<128,128><<<64, 256, 0, stream>>>(pW3, wt_p3);
  k_wconv<128,128><<<64, 256, 0, stream>>>(qW,  wt_q);
  k_wconv<128,128><<<64, 256, 0, stream>>>(kW,  wt_k);
  k_wconv<128,128><<<64, 256, 0, stream>>>(vW,  wt_v);
  k_wconv<128,128><<<64, 256, 0, stream>>>(sW,  wt_s);
  k_wconv<128, 64><<<32, 256, 0, stream>>>(uW1, wt_u1);
  k_wconv<64, 128><<<32, 256, 0, stream>>>(uW2, wt_u2);
  k_wconv<128,128><<<64, 256, 0, stream>>>(uW3, wt_u3);

  // --- prep MLP: x -> h16 ---
  gemm_small<F_, 64, true><<<g32, 128, 0, stream>>>(x, pW1, pb1, t1b);
  mfma_gemmN<64, 128, 1, true,  false, true, 1><<<gT, 256, 0, stream>>>(
      t1b, wt_p2, nullptr, nullptr, nullptr, pb2, nullptr, nullptr, nullptr,
      nullptr, t2b, nullptr, nullptr, nullptr);
  mfma_gemmN<128, 128, 1, false, false, true, 1><<<gT, 256, 0, stream>>>(
      t2b, wt_p3, nullptr, nullptr, nullptr, pb3, nullptr, nullptr, nullptr,
      nullptr, h16, nullptr, nullptr, nullptr);

  // --- fused projections: h16 -> q,k,v (bf16) + skip (fp32, into out) ---
  mfma_gemmN<128, 128, 4, false, false, true, 0b0111><<<gT, 256, 0, stream>>>(
      h16, wt_q, wt_k, wt_v, wt_s, qb, kb, vb, sb,
      nullptr, q16, k16, v16, out);

  // --- CSR build (region 0 now free) ---
  k_zero <<<(N_ + 255) / 256, 256, 0, stream>>>(deg);
  k_hist <<<(E_ + 255) / 256, 256, 0, stream>>>(ei, deg);
  k_scan1<<<SCAN_NB, 256, 0, stream>>>(deg, off, bsum);
  k_scan2<<<1, 512, 0, stream>>>(bsum);
  k_scan3<<<SCAN_NB, 256, 0, stream>>>(off, bsum, cur);
  k_fill <<<(E_ + 255) / 256, 256, 0, stream>>>(ei, cur, esrc);

  // --- attention (adds onto skip already in out) ---
  k_attn<<<(N_ + 3) / 4, 256, 0, stream>>>(esrc, off, deg, q16, k16, v16, out);

  // --- update MLP with residual: out = h + mlp(h), h == out ---
  mfma_gemmN<128, 64, 1, true,  false, false, 1><<<gT, 256, 0, stream>>>(
      out, wt_u1, nullptr, nullptr, nullptr, ub1, nullptr, nullptr, nullptr,
      nullptr, t1b, nullptr, nullptr, nullptr);
  mfma_gemmN<64, 128, 1, true,  false, true, 1><<<gT, 256, 0, stream>>>(
      t1b, wt_u2, nullptr, nullptr, nullptr, ub2, nullptr, nullptr, nullptr,
      nullptr, t2b, nullptr, nullptr, nullptr);
  mfma_gemmN<128, 128, 1, false, true, true, 0><<<gT, 256, 0, stream>>>(
      t2b, wt_u3, nullptr, nullptr, nullptr, ub3, nullptr, nullptr, nullptr,
      out, out, nullptr, nullptr, nullptr);
}